// Round 15
// baseline (204.478 us; speedup 1.0000x reference)
//
#include <hip/hip_runtime.h>
#include <hip/hip_bf16.h>

// SimVQ: z[16,1024,64] f32, codebook[16384,64] f32, proj_w[64,64] f32, proj_b[64] f32, scale f32
// Outputs (fp32, concat): quantized_st[1048576], vq_loss[1], idx[16384]
// r15: GEMM passes reconfigured for BOTH low traffic and TLP (r7 had 64tok/wave @2 blk/CU,
// r14 had 32tok/wave @4 blk/CU — both 50µs walls, VALU+LDS each ~50% duty, poorly overlapped):
// 64 tok/wave + 16 splits -> 1024 blocks (4/CU), 8 stages x 128 codes dbuf (fewer barriers),
// LDS bytes/score and per-score VALU halved. mfma2: ONE threshold branch per t-iter.
// Arbiter path (r14-proven): k_scan worklist (serial-scan, 1 atomic/block) -> k_arb (1024
// waves stride worklist, lane-parallel fp64) -> k_out -> k_loss. Margin scheme proven
// r5-r14: pass1 mfma top value, pass2 collect within 8e-3, fp64 arbiter. CAP 16.

#define NCODES 16384
#define NTOK   16384
#define DIM    64
#define MARGIN_MFMA 8e-3f
#define CAP    16

typedef __attribute__((ext_vector_type(8))) short bf16x8;
typedef __attribute__((ext_vector_type(4))) float f32x4;
#define GLOBAL_AS __attribute__((address_space(1)))
#define LDS_AS    __attribute__((address_space(3)))

__device__ float  g_qcb[NCODES * DIM];   // 4 MB projected codebook fp32 (gather source)
__device__ short  g_cnb[NCODES * DIM];   // 2 MB l2norm(qcb) bf16 row-major (MFMA B)
__device__ short  g_znb[NTOK * DIM];     // 2 MB l2norm(z)  bf16 row-major (MFMA A)
__device__ unsigned g_topu[NTOK];        // orderable-encoded mfma top-1 value
__device__ int    g_candcnt[NTOK];
__device__ int    g_cand[NTOK * CAP];    // 1 MB; slot 0 holds the winner after k_arb
__device__ int    g_wl[NTOK];            // flagged-token worklist
__device__ int    g_wln;
__device__ float  g_partial[512];        // per-block loss partials (all written every call)

__device__ __forceinline__ float wave_sum64(float v) {
#pragma unroll
  for (int o = 32; o > 0; o >>= 1) v += __shfl_xor(v, o, 64);
  return v;
}
__device__ __forceinline__ short f2bf(float f) {
  __hip_bfloat16 h = __float2bfloat16(f);
  return *reinterpret_cast<short*>(&h);
}
__device__ __forceinline__ float bf2f(short s) {
  __hip_bfloat16 h = *reinterpret_cast<__hip_bfloat16*>(&s);
  return __bfloat162float(h);
}
__device__ __forceinline__ void split8(const float* v, bf16x8& hi, bf16x8& lo) {
#pragma unroll
  for (int i = 0; i < 8; ++i) {
    float f = v[i];
    short h = f2bf(f);
    hi[i] = h;
    lo[i] = f2bf(f - bf2f(h));
  }
}

// k_prep: blocks [0,256): projection qc = cb@W^T + b via Ozaki hi/lo bf16 MFMA (fp32-class
// accuracy) -> fp32 qcb, bf16 cnb. blocks [256,512): znorm -> bf16 znb + zero per-call state.
__global__ __launch_bounds__(256) void k_prep(const float* __restrict__ cb,
                                              const float* __restrict__ pw,
                                              const float* __restrict__ pb,
                                              const float* __restrict__ z) {
  int tid = threadIdx.x;
  int wave = tid >> 6, lane = tid & 63, quad = lane >> 4, col = lane & 15;
  if (blockIdx.x < 256) {
    int rowBase = blockIdx.x * 64 + wave * 16;
    const float* cr = cb + (size_t)(rowBase + col) * 64 + quad * 8;
    bf16x8 ah0, al0, ah1, al1;
    split8(cr, ah0, al0);
    split8(cr + 32, ah1, al1);
    float vals[4][4];
    float nr[4] = {0.f, 0.f, 0.f, 0.f};
    const f32x4 fz = {0.f, 0.f, 0.f, 0.f};
#pragma unroll
    for (int nt = 0; nt < 4; ++nt) {
      int j = col + 16 * nt;
      const float* wr = pw + (size_t)j * 64 + quad * 8;
      bf16x8 bh0, bl0, bh1, bl1;
      split8(wr, bh0, bl0);
      split8(wr + 32, bh1, bl1);
      f32x4 d = __builtin_amdgcn_mfma_f32_16x16x32_bf16(ah0, bh0, fz, 0, 0, 0);
      d = __builtin_amdgcn_mfma_f32_16x16x32_bf16(ah1, bh1, d, 0, 0, 0);
      d = __builtin_amdgcn_mfma_f32_16x16x32_bf16(ah0, bl0, d, 0, 0, 0);
      d = __builtin_amdgcn_mfma_f32_16x16x32_bf16(ah1, bl1, d, 0, 0, 0);
      d = __builtin_amdgcn_mfma_f32_16x16x32_bf16(al0, bh0, d, 0, 0, 0);
      d = __builtin_amdgcn_mfma_f32_16x16x32_bf16(al1, bh1, d, 0, 0, 0);
      float bj = pb[j];
#pragma unroll
      for (int r = 0; r < 4; ++r) {
        float v = d[r] + bj;
        vals[nt][r] = v;
        nr[r] = fmaf(v, v, nr[r]);
      }
    }
#pragma unroll
    for (int r = 0; r < 4; ++r) {
      float v = nr[r];
      v += __shfl_xor(v, 1, 64);
      v += __shfl_xor(v, 2, 64);
      v += __shfl_xor(v, 4, 64);
      v += __shfl_xor(v, 8, 64);
      nr[r] = 1.0f / fmaxf(sqrtf(v), 1e-12f);
    }
#pragma unroll
    for (int nt = 0; nt < 4; ++nt)
#pragma unroll
      for (int r = 0; r < 4; ++r) {
        int row = rowBase + quad * 4 + r;
        int j = col + 16 * nt;
        g_qcb[(size_t)row * 64 + j] = vals[nt][r];
        g_cnb[(size_t)row * 64 + j] = f2bf(vals[nt][r] * nr[r]);
      }
  } else {
    int zb = blockIdx.x - 256;
    int gid = zb * 256 + tid;
    if (gid < NTOK) { g_topu[gid] = 0u; g_candcnt[gid] = 0; }
    if (gid == 0) g_wln = 0;
    int base = zb * 64;
    for (int r = 0; r < 16; ++r) {
      int row = base + wave * 16 + r;
      float v = z[(size_t)row * 64 + lane];
      float tot = wave_sum64(v * v);
      g_znb[(size_t)row * 64 + lane] = f2bf(v / fmaxf(sqrtf(tot), 1e-12f));
    }
  }
}

// GEMM core: grid = 64 tokBlocks x 16 splits = 1024 blocks (4/CU), 4 waves/block,
// wave owns 64 tokens (4 A-frag pairs -> one B-frag pair feeds 8 MFMAs = 2 B/score LDS).
// B double-buffered 128-code (16KB) stages (8 stages/split) via global_load_lds width-16,
// XOR-swizzled (LDS[row][c] = G[row][c ^ (row&7)]); ONE barrier/stage.
// MFMA layouts (HW-proven): A m=col,k=quad*8+i ; B n=col,k=quad*8+i ; C/D m=quad*4+r,n=col.
__global__ __launch_bounds__(256) void k_mfma1() {
  __shared__ __align__(16) short smB[2][8192];
  int tid = threadIdx.x;
  int wave = tid >> 6, lane = tid & 63;
  int quad = lane >> 4, col = lane & 15;
  int tokBlock = blockIdx.x >> 4, split = blockIdx.x & 15;
  int tokBase = tokBlock * 256 + wave * 64;

  const short* za = g_znb + (size_t)(tokBase + col) * 64 + quad * 8;
  bf16x8 A0[4], A1[4];
#pragma unroll
  for (int f = 0; f < 4; ++f) {
    A0[f] = *(const bf16x8*)(za + f * 16 * 64);
    A1[f] = *(const bf16x8*)(za + f * 16 * 64 + 32);
  }
  float m[4][4];
#pragma unroll
  for (int f = 0; f < 4; ++f)
#pragma unroll
    for (int r = 0; r < 4; ++r) m[f][r] = -3.0e38f;

  const char* gsplit = (const char*)(g_cnb + (size_t)split * 1024 * 64);
  int x = col & 7;
  int s0off = ((quad ^ x) << 3);
  int s1off = (((4 | quad) ^ x) << 3);
  int goff[4];
#pragma unroll
  for (int i = 0; i < 4; ++i) {
    int cidx = wave * 256 + i * 64 + lane;
    int row = cidx >> 3, sw = cidx & 7;
    goff[i] = row * 128 + ((sw ^ (row & 7)) << 4);
  }

#pragma unroll
  for (int i = 0; i < 4; ++i)
    __builtin_amdgcn_global_load_lds((const GLOBAL_AS void*)(gsplit + goff[i]),
                                     (LDS_AS void*)(&smB[0][wave * 2048 + i * 512]), 16, 0, 0);
  __syncthreads();

  int p = 0;
  for (int s = 0; s < 8; ++s) {
    if (s < 7) {
      const char* gb = gsplit + (size_t)(s + 1) * 16384;
#pragma unroll
      for (int i = 0; i < 4; ++i)
        __builtin_amdgcn_global_load_lds((const GLOBAL_AS void*)(gb + goff[i]),
                                         (LDS_AS void*)(&smB[p ^ 1][wave * 2048 + i * 512]),
                                         16, 0, 0);
    }
    const short* bufp = smB[p];
#pragma unroll
    for (int t = 0; t < 8; ++t) {
      const short* lb = bufp + (t * 16 + col) * 64;
      bf16x8 b0 = *(const bf16x8*)(lb + s0off);
      bf16x8 b1 = *(const bf16x8*)(lb + s1off);
#pragma unroll
      for (int f = 0; f < 4; ++f) {
        f32x4 acc = {0.f, 0.f, 0.f, 0.f};
        acc = __builtin_amdgcn_mfma_f32_16x16x32_bf16(A0[f], b0, acc, 0, 0, 0);
        acc = __builtin_amdgcn_mfma_f32_16x16x32_bf16(A1[f], b1, acc, 0, 0, 0);
#pragma unroll
        for (int r = 0; r < 4; ++r) m[f][r] = fmaxf(m[f][r], acc[r]);
      }
    }
    __syncthreads();
    p ^= 1;
  }

#pragma unroll
  for (int f = 0; f < 4; ++f)
#pragma unroll
    for (int r = 0; r < 4; ++r) {
      float v = m[f][r];
      v = fmaxf(v, __shfl_xor(v, 1, 64));
      v = fmaxf(v, __shfl_xor(v, 2, 64));
      v = fmaxf(v, __shfl_xor(v, 4, 64));
      v = fmaxf(v, __shfl_xor(v, 8, 64));
      if (col == 0) {
        unsigned b = __float_as_uint(v);
        unsigned e = (b & 0x80000000u) ? ~b : (b | 0x80000000u);
        atomicMax(&g_topu[tokBase + f * 16 + quad * 4 + r], e);
      }
    }
}

__global__ __launch_bounds__(256) void k_mfma2() {
  __shared__ __align__(16) short smB[2][8192];
  int tid = threadIdx.x;
  int wave = tid >> 6, lane = tid & 63;
  int quad = lane >> 4, col = lane & 15;
  int tokBlock = blockIdx.x >> 4, split = blockIdx.x & 15;
  int tokBase = tokBlock * 256 + wave * 64;

  const short* za = g_znb + (size_t)(tokBase + col) * 64 + quad * 8;
  bf16x8 A0[4], A1[4];
#pragma unroll
  for (int f = 0; f < 4; ++f) {
    A0[f] = *(const bf16x8*)(za + f * 16 * 64);
    A1[f] = *(const bf16x8*)(za + f * 16 * 64 + 32);
  }
  float th[4][4];
#pragma unroll
  for (int f = 0; f < 4; ++f)
#pragma unroll
    for (int r = 0; r < 4; ++r) {
      unsigned u = g_topu[tokBase + f * 16 + quad * 4 + r];
      unsigned b = (u & 0x80000000u) ? (u & 0x7FFFFFFFu) : ~u;
      th[f][r] = __uint_as_float(b) - MARGIN_MFMA;
    }

  const char* gsplit = (const char*)(g_cnb + (size_t)split * 1024 * 64);
  int x = col & 7;
  int s0off = ((quad ^ x) << 3);
  int s1off = (((4 | quad) ^ x) << 3);
  int goff[4];
#pragma unroll
  for (int i = 0; i < 4; ++i) {
    int cidx = wave * 256 + i * 64 + lane;
    int row = cidx >> 3, sw = cidx & 7;
    goff[i] = row * 128 + ((sw ^ (row & 7)) << 4);
  }

#pragma unroll
  for (int i = 0; i < 4; ++i)
    __builtin_amdgcn_global_load_lds((const GLOBAL_AS void*)(gsplit + goff[i]),
                                     (LDS_AS void*)(&smB[0][wave * 2048 + i * 512]), 16, 0, 0);
  __syncthreads();

  int codeB = split * 1024 + col;
  int p = 0;
  for (int s = 0; s < 8; ++s) {
    if (s < 7) {
      const char* gb = gsplit + (size_t)(s + 1) * 16384;
#pragma unroll
      for (int i = 0; i < 4; ++i)
        __builtin_amdgcn_global_load_lds((const GLOBAL_AS void*)(gb + goff[i]),
                                         (LDS_AS void*)(&smB[p ^ 1][wave * 2048 + i * 512]),
                                         16, 0, 0);
    }
    const short* bufp = smB[p];
#pragma unroll
    for (int t = 0; t < 8; ++t) {
      const short* lb = bufp + (t * 16 + col) * 64;
      bf16x8 b0 = *(const bf16x8*)(lb + s0off);
      bf16x8 b1 = *(const bf16x8*)(lb + s1off);
      f32x4 acc[4];
#pragma unroll
      for (int f = 0; f < 4; ++f) {
        f32x4 a = {0.f, 0.f, 0.f, 0.f};
        a = __builtin_amdgcn_mfma_f32_16x16x32_bf16(A0[f], b0, a, 0, 0, 0);
        acc[f] = __builtin_amdgcn_mfma_f32_16x16x32_bf16(A1[f], b1, a, 0, 0, 0);
      }
      // ONE branch per t-iter over all 16 values (rare: ~1.3 appends/token total)
      float dmax = -1.f;
#pragma unroll
      for (int f = 0; f < 4; ++f)
#pragma unroll
        for (int r = 0; r < 4; ++r) dmax = fmaxf(dmax, acc[f][r] - th[f][r]);
      if (dmax >= 0.f) {
        int code = codeB + s * 128 + t * 16;
#pragma unroll
        for (int f = 0; f < 4; ++f)
#pragma unroll
          for (int r = 0; r < 4; ++r) {
            if (acc[f][r] >= th[f][r]) {
              int tok = tokBase + f * 16 + quad * 4 + r;
              int pos = atomicAdd(&g_candcnt[tok], 1);
              if (pos < CAP) g_cand[tok * CAP + pos] = code;
            }
          }
      }
    }
    __syncthreads();
    p ^= 1;
  }
}

// k_scan: build worklist of flagged tokens (cnt >= 2). LDS flags + thread-0 serial
// exclusive scan -> ONE atomicAdd per block.
__global__ __launch_bounds__(256) void k_scan() {
  __shared__ int flags[256];
  __shared__ int sbase;
  int tid = threadIdx.x;
  int tok = blockIdx.x * 256 + tid;
  int flag = (g_candcnt[tok] >= 2) ? 1 : 0;
  flags[tid] = flag;
  __syncthreads();
  if (tid == 0) {
    int run = 0;
    for (int i = 0; i < 256; ++i) {
      int f = flags[i];
      flags[i] = run;  // exclusive prefix
      run += f;
    }
    sbase = atomicAdd(&g_wln, run);
  }
  __syncthreads();
  if (flag) g_wl[sbase + flags[tid]] = tok;
}

// k_arb: resolve flagged tokens. 256 blocks x 4 waves = 1024 waves STRIDE the worklist
// (load-balanced, zero atomics). Per candidate: lane j computes qc_j = b_j + sum_k W[j,k]cb_k
// in fp64 via 4 independent chains; WT layout [k][j] -> lane-stride-1 LDS (conflict-free).
// Score (z.qc)/||qc|| (monotone to ref), tie -> smallest code. Winner -> g_cand[tok*CAP].
__global__ __launch_bounds__(256) void k_arb(const float* __restrict__ z,
                                             const float* __restrict__ cb,
                                             const float* __restrict__ pw,
                                             const float* __restrict__ pb) {
  __shared__ double WT[64 * 65];  // WT[k*65+j] = W[j][k]
  __shared__ float cbl[4][64];
  int tid = threadIdx.x;
  int wave = tid >> 6, lane = tid & 63;
  for (int e = tid; e < 4096; e += 256) {
    int j = e >> 6, k = e & 63;
    WT[k * 65 + j] = (double)pw[e];
  }
  __syncthreads();

  int wln = g_wln;
  double bj = (double)pb[lane];
  int gwave = blockIdx.x * 4 + wave;

  for (int e = gwave; e < wln; e += 1024) {
    int tok = g_wl[e];
    int cnt = g_candcnt[tok];
    double zj = (double)z[(size_t)tok * 64 + lane];
    double best = -1.0e300;
    int bi = 0x7FFFFFFF;
    int lim = (cnt <= CAP) ? cnt : 0;
    for (int c = 0; c < lim; ++c) {
      int code = g_cand[tok * CAP + c];
      cbl[wave][lane] = cb[(size_t)code * 64 + lane];
      double s0 = 0.0, s1 = 0.0, s2 = 0.0, s3 = 0.0;
#pragma unroll
      for (int kk = 0; kk < 16; ++kk) {
        s0 = fma(WT[kk * 65 + lane], (double)cbl[wave][kk], s0);
        s1 = fma(WT[(kk + 16) * 65 + lane], (double)cbl[wave][kk + 16], s1);
        s2 = fma(WT[(kk + 32) * 65 + lane], (double)cbl[wave][kk + 32], s2);
        s3 = fma(WT[(kk + 48) * 65 + lane], (double)cbl[wave][kk + 48], s3);
      }
      double qc = ((s0 + s1) + (s2 + s3)) + bj;
      double s = zj * qc, n2 = qc * qc;
#pragma unroll
      for (int o = 32; o > 0; o >>= 1) {
        s += __shfl_xor(s, o, 64);
        n2 += __shfl_xor(n2, o, 64);
      }
      double key = s / fmax(sqrt(n2), 1e-12);
      if (key > best || (key == best && code < bi)) { best = key; bi = code; }
    }
    if (cnt > CAP) {  // correctness insurance; empirically never (max cnt seen <= 8 at r8)
      for (int code = 0; code < NCODES; ++code) {
        cbl[wave][lane] = cb[(size_t)code * 64 + lane];
        double s0 = 0.0, s1 = 0.0, s2 = 0.0, s3 = 0.0;
#pragma unroll
        for (int kk = 0; kk < 16; ++kk) {
          s0 = fma(WT[kk * 65 + lane], (double)cbl[wave][kk], s0);
          s1 = fma(WT[(kk + 16) * 65 + lane], (double)cbl[wave][kk + 16], s1);
          s2 = fma(WT[(kk + 32) * 65 + lane], (double)cbl[wave][kk + 32], s2);
          s3 = fma(WT[(kk + 48) * 65 + lane], (double)cbl[wave][kk + 48], s3);
        }
        double qc = ((s0 + s1) + (s2 + s3)) + bj;
        double s = zj * qc, n2 = qc * qc;
#pragma unroll
        for (int o = 32; o > 0; o >>= 1) {
          s += __shfl_xor(s, o, 64);
          n2 += __shfl_xor(n2, o, 64);
        }
        double key = s / fmax(sqrt(n2), 1e-12);
        if (key > best || (key == best && code < bi)) { best = key; bi = code; }
      }
    }
    if (lane == 0) g_cand[tok * CAP] = bi;
  }
}

// k_out: gather + straight-through + idx + per-block loss partial (plain stores only).
__global__ __launch_bounds__(256) void k_out(const float* __restrict__ z,
                                             float* __restrict__ out0,
                                             float* __restrict__ out2) {
  __shared__ float ws[4];
  int tid = threadIdx.x;
  int wave = tid >> 6, lane = tid & 63;
  int base = blockIdx.x * 32;
  float lsum = 0.f;
  for (int r = 0; r < 8; ++r) {
    int tok = base + wave * 8 + r;
    int idx = g_cand[tok * CAP];  // winner (k_arb wrote it for flagged; slot0 otherwise)
    float q = g_qcb[(size_t)idx * 64 + lane];
    float zv = z[(size_t)tok * 64 + lane];
    float d = q - zv;
    out0[(size_t)tok * 64 + lane] = zv + d;  // z + (q - z), ref op order
    lsum = fmaf(d, d, lsum);
    if (lane == 0) out2[tok] = (float)idx;
  }
  float tot = wave_sum64(lsum);
  if (lane == 0) ws[wave] = tot;
  __syncthreads();
  if (tid == 0) g_partial[blockIdx.x] = ((ws[0] + ws[1]) + (ws[2] + ws[3]));
}

// k_loss: one wave sums the 512 partials in fixed order -> out1.
__global__ void k_loss(float* __restrict__ out1) {
  int lane = threadIdx.x;
  float s = 0.f;
#pragma unroll
  for (int i = 0; i < 8; ++i) s += g_partial[lane + 64 * i];
  s = wave_sum64(s);
  if (lane == 0) out1[0] = 1.25f * s / 1048576.0f;  // commitment == codebook numerically
}

extern "C" void kernel_launch(void* const* d_in, const int* in_sizes, int n_in,
                              void* d_out, int out_size, void* d_ws, size_t ws_size,
                              hipStream_t stream) {
  const float* z = (const float*)d_in[0];
  const float* cb = (const float*)d_in[1];
  const float* pw = (const float*)d_in[2];
  const float* pb = (const float*)d_in[3];
  // d_in[4] (scale) unused: argmin invariant to positive scale

  float* out0 = (float*)d_out;
  float* out1 = out0 + (size_t)NTOK * DIM;
  float* out2 = out1 + 1;

  hipLaunchKernelGGL(k_prep, dim3(512), dim3(256), 0, stream, cb, pw, pb, z);
  hipLaunchKernelGGL(k_mfma1, dim3(1024), dim3(256), 0, stream);
  hipLaunchKernelGGL(k_mfma2, dim3(1024), dim3(256), 0, stream);
  hipLaunchKernelGGL(k_scan, dim3(64), dim3(256), 0, stream);
  hipLaunchKernelGGL(k_arb, dim3(256), dim3(256), 0, stream, z, cb, pw, pb);
  hipLaunchKernelGGL(k_out, dim3(512), dim3(256), 0, stream, z, out0, out2);
  hipLaunchKernelGGL(k_loss, dim3(1), dim3(64), 0, stream, out1);
}